// Round 3
// baseline (10377.782 us; speedup 1.0000x reference)
//
#include <hip/hip_runtime.h>
#include <cmath>

typedef short bs8 __attribute__((ext_vector_type(8)));
typedef float f32x4 __attribute__((ext_vector_type(4)));

#define NV 32000
#define SLOTH (32 * 1024)
#define NBLK 256

__device__ __forceinline__ float b2f(unsigned short u) {
  union { unsigned int i; float f; } v; v.i = ((unsigned int)u) << 16; return v.f;
}
__device__ __forceinline__ unsigned short f2b(float f) {
  unsigned int u = __float_as_uint(f);
  return (unsigned short)((u + 0x7FFFu + ((u >> 16) & 1u)) >> 16);
}
__device__ __forceinline__ f32x4 mfma16(bs8 a, bs8 b, f32x4 c) {
  return __builtin_amdgcn_mfma_f32_16x16x32_bf16(a, b, c, 0, 0, 0);
}

// sense-reversing grid barrier; bar[0]=count, bar[16]=generation (split lines)
__device__ __forceinline__ void grid_sync(unsigned* bar) {
  __syncthreads();
  if (threadIdx.x == 0) {
    __threadfence();
    unsigned g = __hip_atomic_load(bar + 16, __ATOMIC_RELAXED, __HIP_MEMORY_SCOPE_AGENT);
    if (__hip_atomic_fetch_add(bar, 1u, __ATOMIC_ACQ_REL, __HIP_MEMORY_SCOPE_AGENT) == NBLK - 1) {
      __hip_atomic_store(bar, 0u, __ATOMIC_RELAXED, __HIP_MEMORY_SCOPE_AGENT);
      __hip_atomic_store(bar + 16, g + 1u, __ATOMIC_RELEASE, __HIP_MEMORY_SCOPE_AGENT);
    } else {
      unsigned cur;
      do {
        __builtin_amdgcn_s_sleep(2);
        cur = __hip_atomic_load(bar + 16, __ATOMIC_RELAXED, __HIP_MEMORY_SCOPE_AGENT);
      } while (cur == g);
    }
    __threadfence();
  }
  __syncthreads();
}

// one LSTM cell gate-GEMM + activation phase for a persistent block.
// block owns units u0..u0+3 (16 virtual gate-cols). 8 waves split K (128 each).
// MODE 0: single matrix, weights in LDS wl. MODE 1: W1 global + W2 from wl.
// MODE 2: both W1, W2 global.
template <int MODE>
__device__ __forceinline__ void cell_phase(
    const unsigned short* __restrict__ A1, const unsigned short* __restrict__ W1,
    const unsigned short* __restrict__ A2, const unsigned short* __restrict__ W2,
    const unsigned short* wl, float (*red)[32][17],
    const float* __restrict__ gxrow, const float* __restrict__ bias,
    const float* __restrict__ cprev,
    unsigned short* __restrict__ hout, float* __restrict__ cout) {
  int tid = threadIdx.x;
  int u0 = blockIdx.x * 4;
  int w = tid >> 6, l = tid & 63;
  int col = l & 15;
  int kb = w * 128 + (l >> 4) * 8;
  size_t wrow = (size_t)(col >> 2) * 1024 + u0 + (col & 3);
  f32x4 acc0 = {0.f, 0.f, 0.f, 0.f}, acc1 = {0.f, 0.f, 0.f, 0.f};
  if (MODE == 0) {
    const unsigned short* a1p = A1 + (size_t)col * 1024 + kb;
    const unsigned short* wp = wl + col * 1032 + kb;
#pragma unroll
    for (int kk = 0; kk < 128; kk += 32) {
      bs8 bf = *(const bs8*)(wp + kk);
      acc0 = mfma16(*(const bs8*)(a1p + kk), bf, acc0);
      acc1 = mfma16(*(const bs8*)(a1p + 16 * 1024 + kk), bf, acc1);
    }
  } else {
    const unsigned short* a1p = A1 + (size_t)col * 1024 + kb;
    const unsigned short* w1p = W1 + wrow * 1024 + kb;
    const unsigned short* a2p = A2 + (size_t)col * 1024 + kb;
#pragma unroll
    for (int kk = 0; kk < 128; kk += 32) {
      bs8 b1 = *(const bs8*)(w1p + kk);
      bs8 b2;
      if (MODE == 1) b2 = *(const bs8*)(wl + col * 1032 + kb + kk);
      else           b2 = *(const bs8*)(W2 + wrow * 1024 + kb + kk);
      acc0 = mfma16(*(const bs8*)(a1p + kk), b1, acc0);
      acc1 = mfma16(*(const bs8*)(a1p + 16 * 1024 + kk), b1, acc1);
      acc0 = mfma16(*(const bs8*)(a2p + kk), b2, acc0);
      acc1 = mfma16(*(const bs8*)(a2p + 16 * 1024 + kk), b2, acc1);
    }
  }
#pragma unroll
  for (int r = 0; r < 4; r++) {
    red[w][(l >> 4) * 4 + r][col] = acc0[r];
    red[w][16 + (l >> 4) * 4 + r][col] = acc1[r];
  }
  __syncthreads();
  if (tid < 128) {
    int b_ = tid >> 2, ul = tid & 3, u = u0 + ul;
    float s0 = 0.f, s1 = 0.f, s2 = 0.f, s3 = 0.f;
#pragma unroll
    for (int ww = 0; ww < 8; ww++) {
      s0 += red[ww][b_][ul];      s1 += red[ww][b_][4 + ul];
      s2 += red[ww][b_][8 + ul];  s3 += red[ww][b_][12 + ul];
    }
    if (gxrow) {
      const float* gp = gxrow + (size_t)b_ * 4096 + u;
      s0 += gp[0]; s1 += gp[1024]; s2 += gp[2048]; s3 += gp[3072];
    }
    if (bias) {
      s0 += bias[u]; s1 += bias[u + 1024]; s2 += bias[u + 2048]; s3 += bias[u + 3072];
    }
    float si = 1.f / (1.f + expf(-s0));
    float sf = 1.f / (1.f + expf(-s1));
    float tg = tanhf(s2);
    float so = 1.f / (1.f + expf(-s3));
    float cn = sf * cprev[b_ * 1024 + u] + si * tg;
    float hn = so * tanhf(cn);
    cout[b_ * 1024 + u] = cn;
    hout[b_ * 1024 + u] = f2b(hn);
  }
}

// ---------------- persistent encoder layer (64 steps, weights in LDS) ------
__global__ __launch_bounds__(512) void enc_persistent(
    const unsigned short* __restrict__ W, const float* __restrict__ gx,
    unsigned short* __restrict__ hh, float* __restrict__ ch,
    unsigned* __restrict__ bar) {
  __shared__ unsigned short wl[16 * 1032];
  __shared__ float red[8][32][17];
  int tid = threadIdx.x, u0 = blockIdx.x * 4;
  for (int i = tid; i < 2048; i += 512) {
    int c = i >> 7, c8 = (i & 127) * 8;
    size_t grow = (size_t)(c >> 2) * 1024 + u0 + (c & 3);
    *(bs8*)&wl[c * 1032 + c8] = *(const bs8*)(W + grow * 1024 + c8);
  }
  __syncthreads();
  for (int s = 0; s < 64; s++) {
    cell_phase<0>(hh + (size_t)s * SLOTH, nullptr, nullptr, nullptr, wl, red,
                  gx + (size_t)s * 131072, nullptr, ch + (size_t)s * SLOTH,
                  hh + (size_t)(s + 1) * SLOTH, ch + (size_t)(s + 1) * SLOTH);
    grid_sync(bar);
  }
}

// ---------------- persistent decoder (64 steps: attn, cell0, cell1) --------
__global__ __launch_bounds__(512) void dec_persistent(
    const unsigned short* __restrict__ ak, const unsigned short* __restrict__ enc,
    const float* __restrict__ gx,
    const unsigned short* __restrict__ wD0c, const unsigned short* __restrict__ wDh0,
    const unsigned short* __restrict__ wD1, const unsigned short* __restrict__ wDh1,
    const float* __restrict__ db1, unsigned short* __restrict__ ctxb,
    unsigned short* __restrict__ dh0, float* __restrict__ dc0,
    unsigned short* __restrict__ dh1, float* __restrict__ dc1,
    unsigned* __restrict__ bar) {
  __shared__ unsigned short wl[16 * 1032];   // wDh0 slice cache
  __shared__ float red[8][32][17];
  __shared__ float qs[1024];
  __shared__ float sc[64], pr[64];
  int tid = threadIdx.x, u0 = blockIdx.x * 4;
  for (int i = tid; i < 2048; i += 512) {
    int c = i >> 7, c8 = (i & 127) * 8;
    size_t grow = (size_t)(c >> 2) * 1024 + u0 + (c & 3);
    *(bs8*)&wl[c * 1032 + c8] = *(const bs8*)(wDh0 + grow * 1024 + c8);
  }
  int w = tid >> 6, l = tid & 63;
  for (int t = 0; t < 64; t++) {
    // ---- phase A: attention (blocks 0..31, block = batch) ----
    if (blockIdx.x < 32) {
      int b = blockIdx.x;
      const unsigned short* q = dh1 + (size_t)t * SLOTH + (size_t)b * 1024;
      {
        ushort2 u2 = *(const ushort2*)&q[tid * 2];
        qs[tid * 2] = b2f(u2.x); qs[tid * 2 + 1] = b2f(u2.y);
      }
      __syncthreads();
      for (int ss = 0; ss < 8; ss++) {
        int s = w * 8 + ss;
        const unsigned short* kr = ak + (size_t)(s * 32 + b) * 1024;
        float p = 0.f;
#pragma unroll
        for (int i = 0; i < 4; i++) {
          int e = (l + i * 64) * 4;
          ushort4 u4 = *(const ushort4*)&kr[e];
          p += qs[e] * b2f(u4.x) + qs[e + 1] * b2f(u4.y)
             + qs[e + 2] * b2f(u4.z) + qs[e + 3] * b2f(u4.w);
        }
        for (int off = 32; off; off >>= 1) p += __shfl_down(p, off);
        if (l == 0) sc[s] = p;
      }
      __syncthreads();
      if (tid < 64) {
        float v = sc[tid], m = v;
        for (int off = 32; off; off >>= 1) m = fmaxf(m, __shfl_xor(m, off));
        float e = expf(v - m), su = e;
        for (int off = 32; off; off >>= 1) su += __shfl_xor(su, off);
        pr[tid] = e / su;
      }
      __syncthreads();
      int c2 = tid * 2;
      float a0 = 0.f, a1 = 0.f;
#pragma unroll 8
      for (int s = 0; s < 64; s++) {
        float p = pr[s];
        ushort2 u2 = *(const ushort2*)&enc[(size_t)(s * 32 + b) * 1024 + c2];
        a0 += p * b2f(u2.x); a1 += p * b2f(u2.y);
      }
      ushort2 o2{f2b(a0), f2b(a1)};
      *(ushort2*)&ctxb[(size_t)b * 1024 + c2] = o2;
    }
    grid_sync(bar);
    // ---- phase B: cell0 (ctx @ wD0c^T + h0 @ wDh0^T + gx) ----
    cell_phase<1>(ctxb, wD0c, dh0 + (size_t)t * SLOTH, nullptr, wl, red,
                  gx + (size_t)t * 131072, nullptr, dc0 + (size_t)t * SLOTH,
                  dh0 + (size_t)(t + 1) * SLOTH, dc0 + (size_t)(t + 1) * SLOTH);
    grid_sync(bar);
    // ---- phase C: cell1 (h0new @ wD1^T + h1 @ wDh1^T + db1) ----
    cell_phase<2>(dh0 + (size_t)(t + 1) * SLOTH, wD1, dh1 + (size_t)t * SLOTH, wDh1,
                  nullptr, red, nullptr, db1, dc1 + (size_t)t * SLOTH,
                  dh1 + (size_t)(t + 1) * SLOTH, dc1 + (size_t)(t + 1) * SLOTH);
    grid_sync(bar);
  }
}

// ---------------- merged f32 -> bf16 weight conversion ---------------------
struct CvtDesc { const float* src; unsigned short* dst; int total8, cols, ld, col0, blk0; };
struct CvtArgs { CvtDesc d[11]; };
__global__ __launch_bounds__(256) void cvt_all(CvtArgs a) {
  int blk = blockIdx.x, seg = 0;
#pragma unroll
  for (int i = 1; i < 11; i++) if (blk >= a.d[i].blk0) seg = i;
  CvtDesc d = a.d[seg];
  int idx = (blk - d.blk0) * 256 + threadIdx.x;
  if (idx >= d.total8) return;
  int cpr = d.cols >> 3;
  int r = idx / cpr, c8 = (idx - r * cpr) * 8;
  const float* s = d.src + (size_t)r * d.ld + d.col0 + c8;
  float4 x = *(const float4*)s, y = *(const float4*)(s + 4);
  unsigned short o[8] = {f2b(x.x), f2b(x.y), f2b(x.z), f2b(x.w),
                         f2b(y.x), f2b(y.y), f2b(y.z), f2b(y.w)};
  *(bs8*)(d.dst + (size_t)r * d.cols + c8) = *(bs8*)o;
}

// ---------------- embedding gather -> bf16 ---------------------------------
__global__ __launch_bounds__(256) void embed_kernel(
    const int* __restrict__ src, const int* __restrict__ prev,
    const float* __restrict__ emb,
    unsigned short* __restrict__ se, unsigned short* __restrict__ te) {
  int idx = blockIdx.x * 256 + threadIdx.x;
  int half = idx >> 17;
  int r = (idx >> 6) & 2047, c8 = (idx & 63) * 8;
  int s = r >> 5, b = r & 31;
  const int* tok = half ? prev : src;
  unsigned short* dst = half ? te : se;
  int t = tok[b * 64 + s];
  const float* e = emb + (size_t)t * 512 + c8;
  float4 a = *(const float4*)e, bb = *(const float4*)(e + 4);
  unsigned short o[8] = {f2b(a.x), f2b(a.y), f2b(a.z), f2b(a.w),
                         f2b(bb.x), f2b(bb.y), f2b(bb.z), f2b(bb.w)};
  *(bs8*)(dst + (size_t)r * 512 + c8) = *(bs8*)o;
}

__global__ __launch_bounds__(256) void zero_init(
    unsigned short* y0h, unsigned short* y1h, float* c0h, float* c1h,
    unsigned* bars) {
  int i = blockIdx.x * 256 + threadIdx.x;
  y0h[i] = 0; y1h[i] = 0; c0h[i] = 0.f; c1h[i] = 0.f;
  if (i < 96) bars[i] = 0u;
}
__global__ __launch_bounds__(256) void init_dec(
    const unsigned short* __restrict__ y0f, const unsigned short* __restrict__ y1f,
    const float* __restrict__ c0f, const float* __restrict__ c1f,
    unsigned short* dh0, unsigned short* dh1, float* dc0, float* dc1) {
  int i = blockIdx.x * 256 + threadIdx.x;
  dh0[i] = y0f[i]; dh1[i] = y1f[i]; dc0[i] = c0f[i]; dc1[i] = c1f[i];
}

// ---------------- bf16 MFMA GEMM (unchanged from round 2) ------------------
template <int OUTMODE>
__global__ __launch_bounds__(256) void gemm_bf16(
    const unsigned short* __restrict__ A, int lda,
    const unsigned short* __restrict__ B, int ldb,
    const float* __restrict__ bias, void* __restrict__ Cp, int ldc, int K) {
  __shared__ unsigned short As[128 * 72];
  __shared__ unsigned short Bs[128 * 72];
  int tid = threadIdx.x;
  int m0 = blockIdx.x * 128, n0 = blockIdx.y * 128;
  int w = tid >> 6, l = tid & 63;
  int wr = w >> 1, wc = w & 1;
  f32x4 acc[4][4];
#pragma unroll
  for (int i = 0; i < 4; i++)
#pragma unroll
    for (int j = 0; j < 4; j++)
#pragma unroll
      for (int r = 0; r < 4; r++) acc[i][j][r] = 0.f;

  for (int k0 = 0; k0 < K; k0 += 64) {
    __syncthreads();
#pragma unroll
    for (int i = 0; i < 4; i++) {
      int idx = tid + i * 256;
      int row = idx >> 3, c8 = (idx & 7) * 8;
      bs8 av = *(const bs8*)(A + (size_t)(m0 + row) * lda + k0 + c8);
      *(bs8*)&As[row * 72 + c8] = av;
      bs8 bv = *(const bs8*)(B + (size_t)(n0 + row) * ldb + k0 + c8);
      *(bs8*)&Bs[row * 72 + c8] = bv;
    }
    __syncthreads();
#pragma unroll
    for (int kk = 0; kk < 2; kk++) {
      bs8 af[4], bfr[4];
#pragma unroll
      for (int i = 0; i < 4; i++)
        af[i] = *(const bs8*)&As[(wr * 64 + i * 16 + (l & 15)) * 72 + kk * 32 + (l >> 4) * 8];
#pragma unroll
      for (int j = 0; j < 4; j++)
        bfr[j] = *(const bs8*)&Bs[(wc * 64 + j * 16 + (l & 15)) * 72 + kk * 32 + (l >> 4) * 8];
#pragma unroll
      for (int i = 0; i < 4; i++)
#pragma unroll
        for (int j = 0; j < 4; j++)
          acc[i][j] = mfma16(af[i], bfr[j], acc[i][j]);
    }
  }
#pragma unroll
  for (int i = 0; i < 4; i++) {
    int mrow = m0 + wr * 64 + i * 16 + (l >> 4) * 4;
#pragma unroll
    for (int j = 0; j < 4; j++) {
      int n = n0 + wc * 64 + j * 16 + (l & 15);
      float bb = bias ? bias[n] : 0.f;
#pragma unroll
      for (int r = 0; r < 4; r++) {
        int m = mrow + r;
        float v = acc[i][j][r] + bb;
        if (OUTMODE == 1)
          ((float*)Cp)[(size_t)(m & 31) * (64ull * NV) + (size_t)(m >> 5) * NV + n] = v;
        else if (OUTMODE == 2)
          ((unsigned short*)Cp)[(size_t)m * ldc + n] = f2b(v);
        else
          ((float*)Cp)[(size_t)m * ldc + n] = v;
      }
    }
  }
}

extern "C" void kernel_launch(void* const* d_in, const int* in_sizes, int n_in,
                              void* d_out, int out_size, void* d_ws, size_t ws_size,
                              hipStream_t stream) {
  (void)in_sizes; (void)n_in; (void)out_size; (void)ws_size;
  const int*   src   = (const int*)d_in[0];
  const int*   prev  = (const int*)d_in[1];
  const float* emb   = (const float*)d_in[2];
  const float* eWih0 = (const float*)d_in[3];
  const float* eWhh0 = (const float*)d_in[4];
  const float* eb0   = (const float*)d_in[5];
  const float* eWih1 = (const float*)d_in[6];
  const float* eWhh1 = (const float*)d_in[7];
  const float* eb1   = (const float*)d_in[8];
  const float* dWih0 = (const float*)d_in[9];
  const float* dWhh0 = (const float*)d_in[10];
  const float* db0   = (const float*)d_in[11];
  const float* dWih1 = (const float*)d_in[12];
  const float* dWhh1 = (const float*)d_in[13];
  const float* db1   = (const float*)d_in[14];
  const float* Wk    = (const float*)d_in[15];
  const float* bk    = (const float*)d_in[16];
  const float* Wh    = (const float*)d_in[17];
  const float* bh    = (const float*)d_in[18];
  float* out = (float*)d_out;

  char* p = (char*)d_ws;
  auto alloc = [&](size_t bytes) {
    char* r = p; p += (bytes + 255) & ~(size_t)255; return r;
  };
  float* gx  = (float*)alloc(2048ull * 4096 * 4);
  float* c0h = (float*)alloc(65ull * SLOTH * 4);
  float* c1h = (float*)alloc(65ull * SLOTH * 4);
  float* dc0 = (float*)alloc(65ull * SLOTH * 4);
  float* dc1 = (float*)alloc(65ull * SLOTH * 4);
  unsigned short* y0h  = (unsigned short*)alloc(65ull * SLOTH * 2);
  unsigned short* y1h  = (unsigned short*)alloc(65ull * SLOTH * 2);
  unsigned short* dh0  = (unsigned short*)alloc(65ull * SLOTH * 2);
  unsigned short* dh1  = (unsigned short*)alloc(65ull * SLOTH * 2);
  unsigned short* se   = (unsigned short*)alloc(2048ull * 512 * 2);
  unsigned short* te   = (unsigned short*)alloc(2048ull * 512 * 2);
  unsigned short* ak   = (unsigned short*)alloc(2048ull * 1024 * 2);
  unsigned short* ctxb = (unsigned short*)alloc(32ull * 1024 * 2);
  unsigned short* wE0  = (unsigned short*)alloc(4096ull * 512 * 2);
  unsigned short* wH0  = (unsigned short*)alloc(4096ull * 1024 * 2);
  unsigned short* wE1  = (unsigned short*)alloc(4096ull * 1024 * 2);
  unsigned short* wH1  = (unsigned short*)alloc(4096ull * 1024 * 2);
  unsigned short* wD0x = (unsigned short*)alloc(4096ull * 512 * 2);
  unsigned short* wD0c = (unsigned short*)alloc(4096ull * 1024 * 2);
  unsigned short* wDh0 = (unsigned short*)alloc(4096ull * 1024 * 2);
  unsigned short* wD1  = (unsigned short*)alloc(4096ull * 1024 * 2);
  unsigned short* wDh1 = (unsigned short*)alloc(4096ull * 1024 * 2);
  unsigned short* wK   = (unsigned short*)alloc(1024ull * 1024 * 2);
  unsigned short* wV   = (unsigned short*)alloc((size_t)NV * 1024 * 2);
  unsigned* bars = (unsigned*)alloc(256 * 4);

  // merged weight conversions
  CvtArgs ca; int nb = 0, ci = 0;
  auto addcvt = [&](const float* s, unsigned short* d, int rows, int cols, int ld, int c0) {
    int t8 = rows * cols / 8;
    ca.d[ci++] = CvtDesc{s, d, t8, cols, ld, c0, nb};
    nb += (t8 + 255) / 256;
  };
  addcvt(eWih0, wE0, 4096, 512, 512, 0);
  addcvt(eWhh0, wH0, 4096, 1024, 1024, 0);
  addcvt(eWih1, wE1, 4096, 1024, 1024, 0);
  addcvt(eWhh1, wH1, 4096, 1024, 1024, 0);
  addcvt(dWih0, wD0x, 4096, 512, 1536, 0);
  addcvt(dWih0, wD0c, 4096, 1024, 1536, 512);
  addcvt(dWhh0, wDh0, 4096, 1024, 1024, 0);
  addcvt(dWih1, wD1, 4096, 1024, 1024, 0);
  addcvt(dWhh1, wDh1, 4096, 1024, 1024, 0);
  addcvt(Wk, wK, 1024, 1024, 1024, 0);
  addcvt(Wh, wV, NV, 1024, 1024, 0);
  cvt_all<<<nb, 256, 0, stream>>>(ca);

  zero_init<<<128, 256, 0, stream>>>(y0h, y1h, c0h, c1h, bars);
  embed_kernel<<<1024, 256, 0, stream>>>(src, prev, emb, se, te);

  // encoder layer 0
  gemm_bf16<0><<<dim3(16, 32), 256, 0, stream>>>(se, 512, wE0, 512, eb0, gx, 4096, 512);
  {
    const unsigned short* W = wH0; const float* g = gx;
    unsigned short* hh = y0h; float* ch = c0h; unsigned* bp = bars;
    void* args[] = {&W, &g, &hh, &ch, &bp};
    hipLaunchCooperativeKernel((void*)enc_persistent, dim3(NBLK), dim3(512), args, 0, stream);
  }
  // encoder layer 1
  gemm_bf16<0><<<dim3(16, 32), 256, 0, stream>>>(y0h + SLOTH, 1024, wE1, 1024, eb1, gx, 4096, 1024);
  {
    const unsigned short* W = wH1; const float* g = gx;
    unsigned short* hh = y1h; float* ch = c1h; unsigned* bp = bars;
    void* args[] = {&W, &g, &hh, &ch, &bp};
    hipLaunchCooperativeKernel((void*)enc_persistent, dim3(NBLK), dim3(512), args, 0, stream);
  }
  // attention keys + decoder input-side gates
  gemm_bf16<2><<<dim3(16, 8), 256, 0, stream>>>(y1h + SLOTH, 1024, wK, 1024, bk, ak, 1024, 1024);
  gemm_bf16<0><<<dim3(16, 32), 256, 0, stream>>>(te, 512, wD0x, 512, db0, gx, 4096, 512);
  init_dec<<<128, 256, 0, stream>>>(y0h + 64 * SLOTH, y1h + 64 * SLOTH,
                                    c0h + 64 * SLOTH, c1h + 64 * SLOTH,
                                    dh0, dh1, dc0, dc1);
  // persistent decoder
  {
    const unsigned short* a = ak; const unsigned short* e = y1h + SLOTH;
    const float* g = gx;
    const unsigned short* p0 = wD0c; const unsigned short* p1 = wDh0;
    const unsigned short* p2 = wD1;  const unsigned short* p3 = wDh1;
    const float* bb = db1; unsigned short* cx = ctxb;
    unsigned short* h0 = dh0; float* q0 = dc0;
    unsigned short* h1 = dh1; float* q1 = dc1; unsigned* bp = bars;
    void* args[] = {&a, &e, &g, &p0, &p1, &p2, &p3, &bb, &cx,
                    &h0, &q0, &h1, &q1, &bp};
    hipLaunchCooperativeKernel((void*)dec_persistent, dim3(NBLK), dim3(512), args, 0, stream);
  }
  // final logits
  gemm_bf16<1><<<dim3(16, 250), 256, 0, stream>>>(dh1 + SLOTH, 1024, wV, 1024, bh, out, NV, 1024);
}

// Round 4
// 3316.123 us; speedup vs baseline: 3.1295x; 3.1295x over previous
//
#include <hip/hip_runtime.h>
#include <cmath>

typedef short bs8 __attribute__((ext_vector_type(8)));
typedef float f32x4 __attribute__((ext_vector_type(4)));

#define NV 32000
#define SLOTH (32 * 1024)

__device__ __forceinline__ float b2f(unsigned short u) {
  union { unsigned int i; float f; } v; v.i = ((unsigned int)u) << 16; return v.f;
}
__device__ __forceinline__ unsigned short f2b(float f) {
  unsigned int u = __float_as_uint(f);
  return (unsigned short)((u + 0x7FFFu + ((u >> 16) & 1u)) >> 16);
}
__device__ __forceinline__ f32x4 mfma16(bs8 a, bs8 b, f32x4 c) {
  return __builtin_amdgcn_mfma_f32_16x16x32_bf16(a, b, c, 0, 0, 0);
}

// ---- shared LSTM cell body: block owns units u0..u0+3 (16 gate-cols), ----
// ---- 8 waves K-split 128 each, LDS reduce, activations by tid<128. --------
template <int DUAL>
__device__ __forceinline__ void cell_body(
    int u0,
    const unsigned short* __restrict__ A1, const unsigned short* __restrict__ W1,
    const unsigned short* __restrict__ A2, const unsigned short* __restrict__ W2,
    const float* __restrict__ gxrow, const float* __restrict__ bias,
    const float* __restrict__ cprev,
    unsigned short* __restrict__ hout, float* __restrict__ cout,
    float (*red)[32][17]) {
  int tid = threadIdx.x;
  int w = tid >> 6, l = tid & 63;
  int col = l & 15;
  int kb = w * 128 + (l >> 4) * 8;
  size_t wrow = (size_t)(col >> 2) * 1024 + u0 + (col & 3);
  f32x4 acc0 = {0.f, 0.f, 0.f, 0.f}, acc1 = {0.f, 0.f, 0.f, 0.f};
  const unsigned short* a1p = A1 + (size_t)col * 1024 + kb;
  const unsigned short* w1p = W1 + wrow * 1024 + kb;
  if (!DUAL) {
#pragma unroll
    for (int kk = 0; kk < 128; kk += 32) {
      bs8 b1 = *(const bs8*)(w1p + kk);
      acc0 = mfma16(*(const bs8*)(a1p + kk), b1, acc0);
      acc1 = mfma16(*(const bs8*)(a1p + 16 * 1024 + kk), b1, acc1);
    }
  } else {
    const unsigned short* a2p = A2 + (size_t)col * 1024 + kb;
    const unsigned short* w2p = W2 + wrow * 1024 + kb;
#pragma unroll
    for (int kk = 0; kk < 128; kk += 32) {
      bs8 b1 = *(const bs8*)(w1p + kk);
      bs8 b2 = *(const bs8*)(w2p + kk);
      acc0 = mfma16(*(const bs8*)(a1p + kk), b1, acc0);
      acc1 = mfma16(*(const bs8*)(a1p + 16 * 1024 + kk), b1, acc1);
      acc0 = mfma16(*(const bs8*)(a2p + kk), b2, acc0);
      acc1 = mfma16(*(const bs8*)(a2p + 16 * 1024 + kk), b2, acc1);
    }
  }
#pragma unroll
  for (int r = 0; r < 4; r++) {
    red[w][(l >> 4) * 4 + r][col] = acc0[r];
    red[w][16 + (l >> 4) * 4 + r][col] = acc1[r];
  }
  __syncthreads();
  if (tid < 128) {
    int b_ = tid >> 2, ul = tid & 3, u = u0 + ul;
    float s0 = 0.f, s1 = 0.f, s2 = 0.f, s3 = 0.f;
#pragma unroll
    for (int ww = 0; ww < 8; ww++) {
      s0 += red[ww][b_][ul];      s1 += red[ww][b_][4 + ul];
      s2 += red[ww][b_][8 + ul];  s3 += red[ww][b_][12 + ul];
    }
    if (gxrow) {
      const float* gp = gxrow + (size_t)b_ * 4096 + u;
      s0 += gp[0]; s1 += gp[1024]; s2 += gp[2048]; s3 += gp[3072];
    }
    if (bias) {
      s0 += bias[u]; s1 += bias[u + 1024]; s2 += bias[u + 2048]; s3 += bias[u + 3072];
    }
    float si = 1.f / (1.f + expf(-s0));
    float sf = 1.f / (1.f + expf(-s1));
    float tg = tanhf(s2);
    float so = 1.f / (1.f + expf(-s3));
    float cn = sf * cprev[b_ * 1024 + u] + si * tg;
    float hn = so * tanhf(cn);
    cout[b_ * 1024 + u] = cn;
    hout[b_ * 1024 + u] = f2b(hn);
  }
}

// ---- decoder cell kernel (grid 256 x 512) ---------------------------------
template <int DUAL>
__global__ __launch_bounds__(512) void cell_kernel(
    const unsigned short* __restrict__ A1, const unsigned short* __restrict__ W1,
    const unsigned short* __restrict__ A2, const unsigned short* __restrict__ W2,
    const float* __restrict__ gxrow, const float* __restrict__ bias,
    const float* __restrict__ cprev,
    unsigned short* __restrict__ hout, float* __restrict__ cout) {
  __shared__ float red[8][32][17];
  cell_body<DUAL>(blockIdx.x * 4, A1, W1, A2, W2, gxrow, bias, cprev, hout, cout, red);
}

// ---- encoder diagonal kernel (grid 512 x 512): layer0 step d | layer1 d-1 -
__global__ __launch_bounds__(512) void enc_diag(
    int d,
    const unsigned short* __restrict__ wH0, const float* __restrict__ gx0,
    unsigned short* __restrict__ y0h, float* __restrict__ c0h,
    const unsigned short* __restrict__ wE1, const unsigned short* __restrict__ wH1,
    const float* __restrict__ eb1,
    unsigned short* __restrict__ y1h, float* __restrict__ c1h) {
  __shared__ float red[8][32][17];
  if (blockIdx.x < 256) {
    if (d >= 64) return;
    cell_body<0>(blockIdx.x * 4,
                 y0h + (size_t)d * SLOTH, wH0, nullptr, nullptr,
                 gx0 + (size_t)d * 131072, nullptr, c0h + (size_t)d * SLOTH,
                 y0h + (size_t)(d + 1) * SLOTH, c0h + (size_t)(d + 1) * SLOTH, red);
  } else {
    if (d < 1) return;
    int j = d - 1;
    cell_body<1>((blockIdx.x - 256) * 4,
                 y0h + (size_t)(j + 1) * SLOTH, wE1,
                 y1h + (size_t)j * SLOTH, wH1,
                 nullptr, eb1, c1h + (size_t)j * SLOTH,
                 y1h + (size_t)(j + 1) * SLOTH, c1h + (size_t)(j + 1) * SLOTH, red);
  }
}

// ---- fused attention: scores -> softmax -> context (32 blocks x 256) ------
__global__ __launch_bounds__(256) void attn_kernel(
    const unsigned short* __restrict__ q, const unsigned short* __restrict__ akey,
    const unsigned short* __restrict__ enc, unsigned short* __restrict__ ctx) {
  int b = blockIdx.x;
  __shared__ float qs[1024];
  __shared__ float sc[64];
  __shared__ float pr[64];
  int tid = threadIdx.x;
  {
    ushort4 u4 = *(const ushort4*)&q[(size_t)b * 1024 + tid * 4];
    qs[tid * 4 + 0] = b2f(u4.x); qs[tid * 4 + 1] = b2f(u4.y);
    qs[tid * 4 + 2] = b2f(u4.z); qs[tid * 4 + 3] = b2f(u4.w);
  }
  __syncthreads();
  int w = tid >> 6, lane = tid & 63;
  for (int ss = 0; ss < 16; ss++) {
    int s = w * 16 + ss;
    const unsigned short* krow = &akey[(size_t)(s * 32 + b) * 1024];
    float p = 0.f;
#pragma unroll
    for (int i = 0; i < 4; i++) {
      int e = (lane + i * 64) * 4;
      ushort4 u4 = *(const ushort4*)&krow[e];
      p += qs[e] * b2f(u4.x) + qs[e + 1] * b2f(u4.y)
         + qs[e + 2] * b2f(u4.z) + qs[e + 3] * b2f(u4.w);
    }
    for (int off = 32; off; off >>= 1) p += __shfl_down(p, off);
    if (lane == 0) sc[s] = p;
  }
  __syncthreads();
  if (tid < 64) {
    float v = sc[tid], m = v;
    for (int off = 32; off; off >>= 1) m = fmaxf(m, __shfl_xor(m, off));
    float e = expf(v - m), su = e;
    for (int off = 32; off; off >>= 1) su += __shfl_xor(su, off);
    pr[tid] = e / su;
  }
  __syncthreads();
  float a0 = 0.f, a1 = 0.f, a2 = 0.f, a3 = 0.f;
  int h4 = tid * 4;
#pragma unroll 8
  for (int s = 0; s < 64; s++) {
    float p = pr[s];
    ushort4 u4 = *(const ushort4*)&enc[(size_t)(s * 32 + b) * 1024 + h4];
    a0 += p * b2f(u4.x); a1 += p * b2f(u4.y); a2 += p * b2f(u4.z); a3 += p * b2f(u4.w);
  }
  ushort4 o{f2b(a0), f2b(a1), f2b(a2), f2b(a3)};
  *(ushort4*)&ctx[(size_t)b * 1024 + h4] = o;
}

// ---- merged f32 -> bf16 weight conversion ---------------------------------
struct CvtDesc { const float* src; unsigned short* dst; int total8, cols, ld, col0, blk0; };
struct CvtArgs { CvtDesc d[11]; };
__global__ __launch_bounds__(256) void cvt_all(CvtArgs a) {
  int blk = blockIdx.x, seg = 0;
#pragma unroll
  for (int i = 1; i < 11; i++) if (blk >= a.d[i].blk0) seg = i;
  CvtDesc d = a.d[seg];
  int idx = (blk - d.blk0) * 256 + threadIdx.x;
  if (idx >= d.total8) return;
  int cpr = d.cols >> 3;
  int r = idx / cpr, c8 = (idx - r * cpr) * 8;
  const float* s = d.src + (size_t)r * d.ld + d.col0 + c8;
  float4 x = *(const float4*)s, y = *(const float4*)(s + 4);
  unsigned short o[8] = {f2b(x.x), f2b(x.y), f2b(x.z), f2b(x.w),
                         f2b(y.x), f2b(y.y), f2b(y.z), f2b(y.w)};
  *(bs8*)(d.dst + (size_t)r * d.cols + c8) = *(bs8*)o;
}

// ---- embedding gather -> bf16 ---------------------------------------------
__global__ __launch_bounds__(256) void embed_kernel(
    const int* __restrict__ src, const int* __restrict__ prev,
    const float* __restrict__ emb,
    unsigned short* __restrict__ se, unsigned short* __restrict__ te) {
  int idx = blockIdx.x * 256 + threadIdx.x;
  int half = idx >> 17;
  int r = (idx >> 6) & 2047, c8 = (idx & 63) * 8;
  int s = r >> 5, b = r & 31;
  const int* tok = half ? prev : src;
  unsigned short* dst = half ? te : se;
  int t = tok[b * 64 + s];
  const float* e = emb + (size_t)t * 512 + c8;
  float4 a = *(const float4*)e, bb = *(const float4*)(e + 4);
  unsigned short o[8] = {f2b(a.x), f2b(a.y), f2b(a.z), f2b(a.w),
                         f2b(bb.x), f2b(bb.y), f2b(bb.z), f2b(bb.w)};
  *(bs8*)(dst + (size_t)r * 512 + c8) = *(bs8*)o;
}

__global__ __launch_bounds__(256) void zero_init(
    unsigned short* y0h, unsigned short* y1h, float* c0h, float* c1h) {
  int i = blockIdx.x * 256 + threadIdx.x;
  y0h[i] = 0; y1h[i] = 0; c0h[i] = 0.f; c1h[i] = 0.f;
}
__global__ __launch_bounds__(256) void init_dec(
    const unsigned short* __restrict__ y0f, const unsigned short* __restrict__ y1f,
    const float* __restrict__ c0f, const float* __restrict__ c1f,
    unsigned short* dh0, unsigned short* dh1, float* dc0, float* dc1) {
  int i = blockIdx.x * 256 + threadIdx.x;
  dh0[i] = y0f[i]; dh1[i] = y1f[i]; dc0[i] = c0f[i]; dc1[i] = c1f[i];
}

// ---- bf16 MFMA GEMM: C[M][N] = A[M][K] * B[N][K]^T + bias -----------------
template <int OUTMODE>
__global__ __launch_bounds__(256) void gemm_bf16(
    const unsigned short* __restrict__ A, int lda,
    const unsigned short* __restrict__ B, int ldb,
    const float* __restrict__ bias, void* __restrict__ Cp, int ldc, int K) {
  __shared__ unsigned short As[128 * 72];
  __shared__ unsigned short Bs[128 * 72];
  int tid = threadIdx.x;
  int m0 = blockIdx.x * 128, n0 = blockIdx.y * 128;
  int w = tid >> 6, l = tid & 63;
  int wr = w >> 1, wc = w & 1;
  f32x4 acc[4][4];
#pragma unroll
  for (int i = 0; i < 4; i++)
#pragma unroll
    for (int j = 0; j < 4; j++)
#pragma unroll
      for (int r = 0; r < 4; r++) acc[i][j][r] = 0.f;

  for (int k0 = 0; k0 < K; k0 += 64) {
    __syncthreads();
#pragma unroll
    for (int i = 0; i < 4; i++) {
      int idx = tid + i * 256;
      int row = idx >> 3, c8 = (idx & 7) * 8;
      bs8 av = *(const bs8*)(A + (size_t)(m0 + row) * lda + k0 + c8);
      *(bs8*)&As[row * 72 + c8] = av;
      bs8 bv = *(const bs8*)(B + (size_t)(n0 + row) * ldb + k0 + c8);
      *(bs8*)&Bs[row * 72 + c8] = bv;
    }
    __syncthreads();
#pragma unroll
    for (int kk = 0; kk < 2; kk++) {
      bs8 af[4], bfr[4];
#pragma unroll
      for (int i = 0; i < 4; i++)
        af[i] = *(const bs8*)&As[(wr * 64 + i * 16 + (l & 15)) * 72 + kk * 32 + (l >> 4) * 8];
#pragma unroll
      for (int j = 0; j < 4; j++)
        bfr[j] = *(const bs8*)&Bs[(wc * 64 + j * 16 + (l & 15)) * 72 + kk * 32 + (l >> 4) * 8];
#pragma unroll
      for (int i = 0; i < 4; i++)
#pragma unroll
        for (int j = 0; j < 4; j++)
          acc[i][j] = mfma16(af[i], bfr[j], acc[i][j]);
    }
  }
#pragma unroll
  for (int i = 0; i < 4; i++) {
    int mrow = m0 + wr * 64 + i * 16 + (l >> 4) * 4;
#pragma unroll
    for (int j = 0; j < 4; j++) {
      int n = n0 + wc * 64 + j * 16 + (l & 15);
      float bb = bias ? bias[n] : 0.f;
#pragma unroll
      for (int r = 0; r < 4; r++) {
        int m = mrow + r;
        float v = acc[i][j][r] + bb;
        if (OUTMODE == 1)
          ((float*)Cp)[(size_t)(m & 31) * (64ull * NV) + (size_t)(m >> 5) * NV + n] = v;
        else if (OUTMODE == 2)
          ((unsigned short*)Cp)[(size_t)m * ldc + n] = f2b(v);
        else
          ((float*)Cp)[(size_t)m * ldc + n] = v;
      }
    }
  }
}

extern "C" void kernel_launch(void* const* d_in, const int* in_sizes, int n_in,
                              void* d_out, int out_size, void* d_ws, size_t ws_size,
                              hipStream_t stream) {
  (void)in_sizes; (void)n_in; (void)out_size; (void)ws_size;
  const int*   src   = (const int*)d_in[0];
  const int*   prev  = (const int*)d_in[1];
  const float* emb   = (const float*)d_in[2];
  const float* eWih0 = (const float*)d_in[3];
  const float* eWhh0 = (const float*)d_in[4];
  const float* eb0   = (const float*)d_in[5];
  const float* eWih1 = (const float*)d_in[6];
  const float* eWhh1 = (const float*)d_in[7];
  const float* eb1   = (const float*)d_in[8];
  const float* dWih0 = (const float*)d_in[9];
  const float* dWhh0 = (const float*)d_in[10];
  const float* db0   = (const float*)d_in[11];
  const float* dWih1 = (const float*)d_in[12];
  const float* dWhh1 = (const float*)d_in[13];
  const float* db1   = (const float*)d_in[14];
  const float* Wk    = (const float*)d_in[15];
  const float* bk    = (const float*)d_in[16];
  const float* Wh    = (const float*)d_in[17];
  const float* bh    = (const float*)d_in[18];
  float* out = (float*)d_out;

  char* p = (char*)d_ws;
  auto alloc = [&](size_t bytes) {
    char* r = p; p += (bytes + 255) & ~(size_t)255; return r;
  };
  float* gx0 = (float*)alloc(2048ull * 4096 * 4);
  float* gxd = (float*)alloc(2048ull * 4096 * 4);
  float* c0h = (float*)alloc(65ull * SLOTH * 4);
  float* c1h = (float*)alloc(65ull * SLOTH * 4);
  float* dc0 = (float*)alloc(65ull * SLOTH * 4);
  float* dc1 = (float*)alloc(65ull * SLOTH * 4);
  unsigned short* y0h  = (unsigned short*)alloc(65ull * SLOTH * 2);
  unsigned short* y1h  = (unsigned short*)alloc(65ull * SLOTH * 2);
  unsigned short* dh0  = (unsigned short*)alloc(65ull * SLOTH * 2);
  unsigned short* dh1  = (unsigned short*)alloc(65ull * SLOTH * 2);
  unsigned short* se   = (unsigned short*)alloc(2048ull * 512 * 2);
  unsigned short* te   = (unsigned short*)alloc(2048ull * 512 * 2);
  unsigned short* ak   = (unsigned short*)alloc(2048ull * 1024 * 2);
  unsigned short* ctxb = (unsigned short*)alloc(32ull * 1024 * 2);
  unsigned short* wE0  = (unsigned short*)alloc(4096ull * 512 * 2);
  unsigned short* wH0  = (unsigned short*)alloc(4096ull * 1024 * 2);
  unsigned short* wE1  = (unsigned short*)alloc(4096ull * 1024 * 2);
  unsigned short* wH1  = (unsigned short*)alloc(4096ull * 1024 * 2);
  unsigned short* wD0x = (unsigned short*)alloc(4096ull * 512 * 2);
  unsigned short* wD0c = (unsigned short*)alloc(4096ull * 1024 * 2);
  unsigned short* wDh0 = (unsigned short*)alloc(4096ull * 1024 * 2);
  unsigned short* wD1  = (unsigned short*)alloc(4096ull * 1024 * 2);
  unsigned short* wDh1 = (unsigned short*)alloc(4096ull * 1024 * 2);
  unsigned short* wK   = (unsigned short*)alloc(1024ull * 1024 * 2);
  unsigned short* wV   = (unsigned short*)alloc((size_t)NV * 1024 * 2);

  // merged weight conversions
  CvtArgs ca; int nb = 0, ci = 0;
  auto addcvt = [&](const float* s, unsigned short* d, int rows, int cols, int ld, int c0) {
    int t8 = rows * cols / 8;
    ca.d[ci++] = CvtDesc{s, d, t8, cols, ld, c0, nb};
    nb += (t8 + 255) / 256;
  };
  addcvt(eWih0, wE0, 4096, 512, 512, 0);
  addcvt(eWhh0, wH0, 4096, 1024, 1024, 0);
  addcvt(eWih1, wE1, 4096, 1024, 1024, 0);
  addcvt(eWhh1, wH1, 4096, 1024, 1024, 0);
  addcvt(dWih0, wD0x, 4096, 512, 1536, 0);
  addcvt(dWih0, wD0c, 4096, 1024, 1536, 512);
  addcvt(dWhh0, wDh0, 4096, 1024, 1024, 0);
  addcvt(dWih1, wD1, 4096, 1024, 1024, 0);
  addcvt(dWhh1, wDh1, 4096, 1024, 1024, 0);
  addcvt(Wk, wK, 1024, 1024, 1024, 0);
  addcvt(Wh, wV, NV, 1024, 1024, 0);
  cvt_all<<<nb, 256, 0, stream>>>(ca);

  zero_init<<<128, 256, 0, stream>>>(y0h, y1h, c0h, c1h);
  embed_kernel<<<1024, 256, 0, stream>>>(src, prev, emb, se, te);

  // input-side gate GEMMs (enc layer0 from se; dec layer0 x-part from te)
  gemm_bf16<0><<<dim3(16, 32), 256, 0, stream>>>(se, 512, wE0, 512, eb0, gx0, 4096, 512);
  gemm_bf16<0><<<dim3(16, 32), 256, 0, stream>>>(te, 512, wD0x, 512, db0, gxd, 4096, 512);

  // encoder: 65 diagonal launches (layer0 step d || layer1 step d-1)
  for (int d = 0; d <= 64; d++)
    enc_diag<<<512, 512, 0, stream>>>(d, wH0, gx0, y0h, c0h, wE1, wH1, eb1, y1h, c1h);

  // attention keys
  gemm_bf16<2><<<dim3(16, 8), 256, 0, stream>>>(y1h + SLOTH, 1024, wK, 1024, bk, ak, 1024, 1024);
  // decoder initial states = encoder finals
  init_dec<<<128, 256, 0, stream>>>(y0h + 64 * SLOTH, y1h + 64 * SLOTH,
                                    c0h + 64 * SLOTH, c1h + 64 * SLOTH,
                                    dh0, dh1, dc0, dc1);
  // decoder: 3 launches per step
  for (int t = 0; t < 64; t++) {
    attn_kernel<<<32, 256, 0, stream>>>(dh1 + (size_t)t * SLOTH, ak, y1h + SLOTH, ctxb);
    cell_kernel<1><<<256, 512, 0, stream>>>(
        ctxb, wD0c, dh0 + (size_t)t * SLOTH, wDh0,
        gxd + (size_t)t * 131072, nullptr, dc0 + (size_t)t * SLOTH,
        dh0 + (size_t)(t + 1) * SLOTH, dc0 + (size_t)(t + 1) * SLOTH);
    cell_kernel<1><<<256, 512, 0, stream>>>(
        dh0 + (size_t)(t + 1) * SLOTH, wD1, dh1 + (size_t)t * SLOTH, wDh1,
        nullptr, db1, dc1 + (size_t)t * SLOTH,
        dh1 + (size_t)(t + 1) * SLOTH, dc1 + (size_t)(t + 1) * SLOTH);
  }
  // final logits: [2048,1024] x [1024,32000]^T scattered to out[b][t][v]
  gemm_bf16<1><<<dim3(16, 250), 256, 0, stream>>>(dh1 + SLOTH, 1024, wV, 1024, bh, out, NV, 1024);
}